// Round 2
// baseline (359.740 us; speedup 1.0000x reference)
//
#include <hip/hip_runtime.h>
#include <math.h>

// Problem constants (B=4, S=4096, H=4096, E=64, top_k=8)
#define TOKENS 16384   // B*S
#define HDIM   4096
#define NEXP   64
#define TOPK   8

#define BM 64
#define BK 64
#define LDA 66   // padded LDS stride in DOUBLES (even -> 16B-aligned double2)
#define LDW 66

// ---- GEMM with fp64 accumulation: logits[t][e] = dot(hidden[t][:], weight[e][:]) ----
// fp32 inputs are converted to double at LDS-staging time (conversion count is
// 1/32 of the MAC count, negligible); the inner loop is pure v_fma_f64 so the
// accumulation order error vs. true value is ~2^-52 -- top-k ordering then
// matches any high-precision reference except for exact ties.
__global__ __launch_bounds__(256) void router_gemm(const float* __restrict__ hid,
                                                   const float* __restrict__ wgt,
                                                   float* __restrict__ logits) {
    __shared__ double As[BM * LDA];
    __shared__ double Ws[NEXP * LDW];

    const int t  = threadIdx.x;
    const int tx = t & 15;        // 0..15 -> expert group (4 experts each)
    const int ty = t >> 4;        // 0..15 -> token group
    const int bm = blockIdx.x * BM;

    double acc[4][4];
#pragma unroll
    for (int i = 0; i < 4; ++i)
#pragma unroll
        for (int j = 0; j < 4; ++j) acc[i][j] = 0.0;

    float4 ra[4], rw[4], ra2[4], rw2[4];

#pragma unroll
    for (int i = 0; i < 4; ++i) {
        ra[i] = *reinterpret_cast<const float4*>(&hid[(size_t)(bm + ty + 16 * i) * HDIM + tx * 4]);
        rw[i] = *reinterpret_cast<const float4*>(&wgt[(size_t)(ty + 16 * i) * HDIM + tx * 4]);
    }

    for (int k0 = 0; k0 < HDIM; k0 += BK) {
        // staged regs -> LDS, converting fp32 -> fp64
#pragma unroll
        for (int i = 0; i < 4; ++i) {
            double* pa = &As[(ty + 16 * i) * LDA + tx * 4];
            double* pw = &Ws[(ty + 16 * i) * LDW + tx * 4];
            *reinterpret_cast<double2*>(pa + 0) = make_double2((double)ra[i].x, (double)ra[i].y);
            *reinterpret_cast<double2*>(pa + 2) = make_double2((double)ra[i].z, (double)ra[i].w);
            *reinterpret_cast<double2*>(pw + 0) = make_double2((double)rw[i].x, (double)rw[i].y);
            *reinterpret_cast<double2*>(pw + 2) = make_double2((double)rw[i].z, (double)rw[i].w);
        }
        __syncthreads();

        // prefetch next K-tile while computing this one
        if (k0 + BK < HDIM) {
#pragma unroll
            for (int i = 0; i < 4; ++i) {
                ra2[i] = *reinterpret_cast<const float4*>(&hid[(size_t)(bm + ty + 16 * i) * HDIM + (k0 + BK) + tx * 4]);
                rw2[i] = *reinterpret_cast<const float4*>(&wgt[(size_t)(ty + 16 * i) * HDIM + (k0 + BK) + tx * 4]);
            }
        }

        // compute: 2 k-values per iteration, double2 (b128) LDS reads
#pragma unroll
        for (int kk = 0; kk < BK; kk += 2) {
            double2 a[4], b[4];
#pragma unroll
            for (int i = 0; i < 4; ++i)
                a[i] = *reinterpret_cast<const double2*>(&As[(ty * 4 + i) * LDA + kk]);
#pragma unroll
            for (int j = 0; j < 4; ++j)
                b[j] = *reinterpret_cast<const double2*>(&Ws[(tx * 4 + j) * LDW + kk]);
#pragma unroll
            for (int i = 0; i < 4; ++i)
#pragma unroll
                for (int j = 0; j < 4; ++j) {
                    acc[i][j] = fma(a[i].x, b[j].x, acc[i][j]);
                    acc[i][j] = fma(a[i].y, b[j].y, acc[i][j]);
                }
        }
        __syncthreads();

#pragma unroll
        for (int i = 0; i < 4; ++i) { ra[i] = ra2[i]; rw[i] = rw2[i]; }
    }

    // epilogue: round to fp32, coalesced float4 stores
#pragma unroll
    for (int i = 0; i < 4; ++i) {
        float4 v = make_float4((float)acc[i][0], (float)acc[i][1],
                               (float)acc[i][2], (float)acc[i][3]);
        *reinterpret_cast<float4*>(&logits[(size_t)(bm + ty * 4 + i) * NEXP + tx * 4]) = v;
    }
}

// ---------------- top-k + softmax: one wave (64 lanes) per token ----------------
__global__ __launch_bounds__(256) void topk_softmax(const float* __restrict__ logits,
                                                    float* __restrict__ out_idx,
                                                    float* __restrict__ out_w) {
    const int wave  = threadIdx.x >> 6;              // 0..3
    const int lane  = threadIdx.x & 63;
    const int token = blockIdx.x * 4 + wave;
    if (token >= TOKENS) return;

    // lane e holds logits[token][e]
    float v = logits[(size_t)token * NEXP + lane];

    float myval = 0.f;   // lane k (<TOPK) ends holding k-th largest value
    int   myidx = 0;     // and its expert index
    float max0  = 0.f;

#pragma unroll
    for (int k = 0; k < TOPK; ++k) {
        float bv = v;
        int   bi = lane;
        // butterfly argmax with tie -> lower index (matches jax.lax.top_k)
#pragma unroll
        for (int off = 32; off > 0; off >>= 1) {
            float ov = __shfl_xor(bv, off);
            int   oi = __shfl_xor(bi, off);
            if (ov > bv || (ov == bv && oi < bi)) { bv = ov; bi = oi; }
        }
        if (k == 0) max0 = bv;
        if (lane == k) { myval = bv; myidx = bi; }
        if (lane == bi) v = -INFINITY;   // remove winner
    }

    // softmax over the 8 winners (held by lanes 0..7); max0 == largest
    float e = (lane < TOPK) ? expf(myval - max0) : 0.f;
    float s = e;
#pragma unroll
    for (int off = 4; off > 0; off >>= 1) s += __shfl_xor(s, off);  // sum within 8-lane group

    if (lane < TOPK) {
        size_t o = (size_t)token * TOPK + lane;
        out_idx[o] = (float)myidx;   // indices stored as float (d_out is float*)
        out_w[o]   = e / s;
    }
}

extern "C" void kernel_launch(void* const* d_in, const int* in_sizes, int n_in,
                              void* d_out, int out_size, void* d_ws, size_t ws_size,
                              hipStream_t stream) {
    const float* hid = (const float*)d_in[0];
    const float* wgt = (const float*)d_in[1];

    float* logits  = (float*)d_out;
    float* out_idx = logits + (size_t)TOKENS * NEXP;
    float* out_w   = out_idx + (size_t)TOKENS * TOPK;

    router_gemm<<<TOKENS / BM, 256, 0, stream>>>(hid, wgt, logits);
    topk_softmax<<<TOKENS / 4, 256, 0, stream>>>(logits, out_idx, out_w);
}

// Round 4
// 193.149 us; speedup vs baseline: 1.8625x; 1.8625x over previous
//
#include <hip/hip_runtime.h>
#include <math.h>

// Problem constants (B=4, S=4096, H=4096, E=64, top_k=8)
#define TOKENS 16384   // B*S
#define HDIM   4096
#define NEXP   64
#define TOPK   8

#define BM 32          // tokens per block
#define BK 32          // K-chunk (in elements)
#define LDA 33         // LDS row stride in doubles
#define CHUNKS (HDIM / BK)

typedef double f64x4 __attribute__((ext_vector_type(4)));

// ---- fp64-MFMA GEMM: logits[t][e] = dot(hidden[t][:], weight[e][:]) ----
// fp64 accumulation => top-k ordering matches the fp64 numpy reference.
// The C/D fragment layout of v_mfma_f64_16x16x4f64 is NOT trusted: it is
// recovered at runtime by two probe MFMAs (works for any bijective layout).
//   probe-row: A[i][k]=i (lane value lane&15), B=1  -> D[i][j] = K*i = 4*i
//   probe-col: A=1, B[k][j]=j (lane value lane&15)  -> D[i][j] = 4*j
__global__ __launch_bounds__(256) void router_gemm_mfma(const float* __restrict__ hid,
                                                        const float* __restrict__ wgt,
                                                        float* __restrict__ logits) {
    __shared__ double As[2][BM * LDA];    // 2 x 32 x 33 doubles = 16.9 KB
    __shared__ double Ws[2][NEXP * LDA];  // 2 x 64 x 33 doubles = 33.8 KB

    const int tid  = threadIdx.x;
    const int bm   = blockIdx.x * BM;

    const int wv   = tid >> 6;       // wave 0..3
    const int lane = tid & 63;
    const int tg   = wv & 1;         // token group: rows tg*16 .. tg*16+15
    const int eh   = wv >> 1;        // expert half: cols eh*32 .. eh*32+31
    const int r    = lane & 15;      // operand free index within 16
    const int kq   = lane >> 4;      // k-slot within K=4 step

    // ---- layout self-calibration probes ----
    f64x4 rowp = {0., 0., 0., 0.};
    f64x4 colp = {0., 0., 0., 0.};
    rowp = __builtin_amdgcn_mfma_f64_16x16x4f64((double)r, 1.0, rowp, 0, 0, 0);
    colp = __builtin_amdgcn_mfma_f64_16x16x4f64(1.0, (double)r, colp, 0, 0, 0);
    int drow[4], dcol[4];
#pragma unroll
    for (int j = 0; j < 4; ++j) {
        drow[j] = (int)(rowp[j] * 0.25 + 0.5);   // exact multiples of 4 -> row 0..15
        dcol[j] = (int)(colp[j] * 0.25 + 0.5);   // -> col 0..15
    }

    f64x4 acc0 = {0., 0., 0., 0.};
    f64x4 acc1 = {0., 0., 0., 0.};

    // staging decomposition: As = 32 rows x 8 float4; Ws = 64 rows x 8 float4 (2/thread)
    const int arow = tid >> 3;       // 0..31
    const int aq   = tid & 7;        // 0..7
    const int wrow = tid >> 3;       // 0..31 (plus +32 row)
    const int wq   = tid & 7;

    float4 pa, pw0, pw1;

    // ---- prologue: chunk 0 -> LDS[0] ----
    pa  = *reinterpret_cast<const float4*>(&hid[(size_t)(bm + arow) * HDIM + aq * 4]);
    pw0 = *reinterpret_cast<const float4*>(&wgt[(size_t)wrow * HDIM + wq * 4]);
    pw1 = *reinterpret_cast<const float4*>(&wgt[(size_t)(wrow + 32) * HDIM + wq * 4]);
    {
        double* a = &As[0][arow * LDA + aq * 4];
        a[0] = pa.x; a[1] = pa.y; a[2] = pa.z; a[3] = pa.w;
        double* w0 = &Ws[0][wrow * LDA + wq * 4];
        w0[0] = pw0.x; w0[1] = pw0.y; w0[2] = pw0.z; w0[3] = pw0.w;
        double* w1 = &Ws[0][(wrow + 32) * LDA + wq * 4];
        w1[0] = pw1.x; w1[1] = pw1.y; w1[2] = pw1.z; w1[3] = pw1.w;
    }

    int cur = 0;
    for (int c = 0; c < CHUNKS; ++c) {
        __syncthreads();   // LDS[cur] fully written

        // prefetch next chunk (latency hides under the MFMA cluster)
        if (c + 1 < CHUNKS) {
            const int k0n = (c + 1) * BK;
            pa  = *reinterpret_cast<const float4*>(&hid[(size_t)(bm + arow) * HDIM + k0n + aq * 4]);
            pw0 = *reinterpret_cast<const float4*>(&wgt[(size_t)wrow * HDIM + k0n + wq * 4]);
            pw1 = *reinterpret_cast<const float4*>(&wgt[(size_t)(wrow + 32) * HDIM + k0n + wq * 4]);
        }

        // compute: 8 K4-steps x 2 MFMA
        const double* Ab  = &As[cur][(tg * 16 + r) * LDA + kq];
        const double* Wb0 = &Ws[cur][(eh * 32 + r) * LDA + kq];
        const double* Wb1 = Wb0 + 16 * LDA;
#pragma unroll
        for (int ks = 0; ks < 8; ++ks) {
            double a  = Ab[ks * 4];
            double b0 = Wb0[ks * 4];
            double b1 = Wb1[ks * 4];
            acc0 = __builtin_amdgcn_mfma_f64_16x16x4f64(a, b0, acc0, 0, 0, 0);
            acc1 = __builtin_amdgcn_mfma_f64_16x16x4f64(a, b1, acc1, 0, 0, 0);
        }

        // write prefetched chunk into the other buffer (reads of it happen only
        // after the next barrier; current-buffer readers untouched)
        if (c + 1 < CHUNKS) {
            double* a = &As[cur ^ 1][arow * LDA + aq * 4];
            a[0] = pa.x; a[1] = pa.y; a[2] = pa.z; a[3] = pa.w;
            double* w0 = &Ws[cur ^ 1][wrow * LDA + wq * 4];
            w0[0] = pw0.x; w0[1] = pw0.y; w0[2] = pw0.z; w0[3] = pw0.w;
            double* w1 = &Ws[cur ^ 1][(wrow + 32) * LDA + wq * 4];
            w1[0] = pw1.x; w1[1] = pw1.y; w1[2] = pw1.z; w1[3] = pw1.w;
        }
        cur ^= 1;
    }

    // ---- epilogue: probe-derived scatter of the C/D fragment ----
#pragma unroll
    for (int j = 0; j < 4; ++j) {
        const int row = bm + tg * 16 + drow[j];
        const int c0  = eh * 32 + dcol[j];
        logits[(size_t)row * NEXP + c0]      = (float)acc0[j];
        logits[(size_t)row * NEXP + c0 + 16] = (float)acc1[j];
    }
}

// ---------------- top-k + softmax: one wave (64 lanes) per token ----------------
__global__ __launch_bounds__(256) void topk_softmax(const float* __restrict__ logits,
                                                    float* __restrict__ out_idx,
                                                    float* __restrict__ out_w) {
    const int wave  = threadIdx.x >> 6;              // 0..3
    const int lane  = threadIdx.x & 63;
    const int token = blockIdx.x * 4 + wave;
    if (token >= TOKENS) return;

    float v = logits[(size_t)token * NEXP + lane];

    float myval = 0.f;
    int   myidx = 0;
    float max0  = 0.f;

#pragma unroll
    for (int k = 0; k < TOPK; ++k) {
        float bv = v;
        int   bi = lane;
#pragma unroll
        for (int off = 32; off > 0; off >>= 1) {   // argmax, tie -> lower index
            float ov = __shfl_xor(bv, off);
            int   oi = __shfl_xor(bi, off);
            if (ov > bv || (ov == bv && oi < bi)) { bv = ov; bi = oi; }
        }
        if (k == 0) max0 = bv;
        if (lane == k) { myval = bv; myidx = bi; }
        if (lane == bi) v = -INFINITY;
    }

    float e = (lane < TOPK) ? expf(myval - max0) : 0.f;
    float s = e;
#pragma unroll
    for (int off = 4; off > 0; off >>= 1) s += __shfl_xor(s, off);

    if (lane < TOPK) {
        size_t o = (size_t)token * TOPK + lane;
        out_idx[o] = (float)myidx;
        out_w[o]   = e / s;
    }
}

extern "C" void kernel_launch(void* const* d_in, const int* in_sizes, int n_in,
                              void* d_out, int out_size, void* d_ws, size_t ws_size,
                              hipStream_t stream) {
    const float* hid = (const float*)d_in[0];
    const float* wgt = (const float*)d_in[1];

    float* logits  = (float*)d_out;
    float* out_idx = logits + (size_t)TOKENS * NEXP;
    float* out_w   = out_idx + (size_t)TOKENS * TOPK;

    router_gemm_mfma<<<TOKENS / BM, 256, 0, stream>>>(hid, wgt, logits);
    topk_softmax<<<TOKENS / 4, 256, 0, stream>>>(logits, out_idx, out_w);
}